// Round 14
// baseline (1112.212 us; speedup 1.0000x reference)
//
#include <hip/hip_runtime.h>
#include <math.h>

#define NN 50000
#define NE 800000
#define NWGE1 (NE / 128)  // 6250 edge blocks (mlp1)
#define NWGE2 (NE / 256)  // 3125 edge blocks (mlp2)

typedef short bf8 __attribute__((ext_vector_type(8)));
typedef short bf4v __attribute__((ext_vector_type(4)));
typedef short bf2v __attribute__((ext_vector_type(2)));
typedef float f4 __attribute__((ext_vector_type(4)));

// float -> bf16 bits, round-to-nearest-even (values are finite)
__device__ __forceinline__ short f2b(float f) {
  unsigned int u = __float_as_uint(f);
  unsigned int r = (u + 0x7FFFu + ((u >> 16) & 1u)) >> 16;
  return (short)(unsigned short)r;
}
__device__ __forceinline__ float b2f(short s) {
  return __uint_as_float(((unsigned int)(unsigned short)s) << 16);
}
__device__ __forceinline__ f4 b2f4(bf4v p) {
  f4 v;
  v[0] = b2f(p[0]); v[1] = b2f(p[1]); v[2] = b2f(p[2]); v[3] = b2f(p[3]);
  return v;
}

// bijective XCD-aware swizzle (8 XCDs): blocks on the same XCD get a
// CONTIGUOUS range of dst-sorted edge chunks -> dst gather/atomics localize.
__device__ __forceinline__ int swz8(int b, int nwg) {
  const int q = nwg >> 3, r = nwg & 7;
  const int x = b & 7, o = b >> 3;
  return (x < r ? x * (q + 1) : r * (q + 1) + (x - r) * q) + o;
}

// ---------------- merged preprocessing: 6 transposes + nf convert + degree ----
// blocks [0,1024): weight transpose+cvt; [1024,7274): nf cvt; [7274,10399): cnt

__global__ __launch_bounds__(256) void prep_k(
    const float* __restrict__ Wr1a, const float* __restrict__ Wr1b,
    const float* __restrict__ We2,  const float* __restrict__ Wr2a,
    const float* __restrict__ Wr2b, const float* __restrict__ Wl1,
    short* __restrict__ WaT1, short* __restrict__ WbT1,
    short* __restrict__ We2T, short* __restrict__ WaT2,
    short* __restrict__ WbT2, short* __restrict__ Wl1T,
    const float* __restrict__ nf, short* __restrict__ nfb,
    const int* __restrict__ dst, int* __restrict__ cnt)
{
  const int b = blockIdx.x;
  if (b < 1024) {
    const float* in; short* out; int K, N, bb;
    if (b < 64)       { in = Wr1a; out = WaT1; K = 128; N = 128; bb = b; }
    else if (b < 128) { in = Wr1b; out = WbT1; K = 128; N = 128; bb = b - 64; }
    else if (b < 256) { in = We2;  out = We2T; K = 128; N = 256; bb = b - 128; }
    else if (b < 512) { in = Wr2a; out = WaT2; K = 256; N = 256; bb = b - 256; }
    else if (b < 768) { in = Wr2b; out = WbT2; K = 256; N = 256; bb = b - 512; }
    else              { in = Wl1;  out = Wl1T; K = 256; N = 256; bb = b - 768; }
    const int i = bb * 256 + threadIdx.x;
    if (i < K * N) {
      const int n = i / K, k = i - n * K;
      out[i] = f2b(in[(size_t)k * N + n]);
    }
  } else if (b < 7274) {
    const int i = (b - 1024) * 256 + threadIdx.x;   // i < NN*128/4 = 1.6M exactly
    f4 v = *(const f4*)&nf[(size_t)i * 4];
    bf4v p;
    p[0] = f2b(v[0]); p[1] = f2b(v[1]); p[2] = f2b(v[2]); p[3] = f2b(v[3]);
    *(bf4v*)&nfb[(size_t)i * 4] = p;
  } else {
    const int e = (b - 7274) * 256 + threadIdx.x;   // e < NE exactly
    atomicAdd(&cnt[dst[e]], 1);
  }
}

// ---------------- per-node inverse norms --------------------------------------
__global__ __launch_bounds__(256) void norm1_k(const short* __restrict__ nfb,
                                               float* __restrict__ invn) {
  const int node = blockIdx.x * 4 + (threadIdx.x >> 6);
  if (node >= NN) return;
  const int lane = threadIdx.x & 63;
  bf2v hb = *(const bf2v*)&nfb[(size_t)node * 128 + lane * 2];
  float h0 = b2f(hb[0]), h1v = b2f(hb[1]);
  float ss = fmaf(h0, h0, h1v * h1v);
#pragma unroll
  for (int o = 32; o >= 1; o >>= 1) ss += __shfl_xor(ss, o);
  if (lane == 0) invn[node] = 1.f / fmaxf(sqrtf(ss), 1e-12f);
}

__global__ __launch_bounds__(256) void norm2_k(const short* __restrict__ h1b,
                                               float* __restrict__ invn) {
  const int node = blockIdx.x * 4 + (threadIdx.x >> 6);
  if (node >= NN) return;
  const int lane = threadIdx.x & 63;
  f4 h = b2f4(*(const bf4v*)&h1b[(size_t)node * 256 + lane * 4]);
  float ss = 0.f;
#pragma unroll
  for (int r = 0; r < 4; ++r) ss = fmaf(h[r], h[r], ss);
#pragma unroll
  for (int o = 32; o >= 1; o >>= 1) ss += __shfl_xor(ss, o);
  if (lane == 0) invn[node] = 1.f / fmaxf(sqrtf(ss), 1e-12f);
}

// ---------------- hierarchical counting-sort scan -----------------------------

__global__ __launch_bounds__(1024) void scanA_k(const int* __restrict__ cnt,
                                                int* __restrict__ off2,
                                                int* __restrict__ bsum) {
  __shared__ int buf[1024];
  const int t = threadIdx.x;
  const int i = blockIdx.x * 1024 + t;
  const int v = (i < NN) ? cnt[i] : 0;
  buf[t] = v;
  __syncthreads();
#pragma unroll
  for (int o = 1; o < 1024; o <<= 1) {
    int x = (t >= o) ? buf[t - o] : 0;
    __syncthreads();
    buf[t] += x;
    __syncthreads();
  }
  if (i < NN) off2[i] = buf[t] - v;
  if (t == 1023) bsum[blockIdx.x] = buf[t];
}

__global__ __launch_bounds__(64) void scanB_k(int* __restrict__ bsum, int nb) {
  const int t = threadIdx.x;
  int v = (t < nb) ? bsum[t] : 0;
#pragma unroll
  for (int o = 1; o < 64; o <<= 1) {
    int x = __shfl_up(v, o);
    if (t >= o) v += x;
  }
  if (t < nb) bsum[t] = v;   // inclusive totals
}

__global__ __launch_bounds__(256) void scanC_k(int* __restrict__ off2,
                                               const int* __restrict__ bsum) {
  const int i = blockIdx.x * 256 + threadIdx.x;
  if (i >= NN) return;
  const int b = i >> 10;
  if (b) off2[i] += bsum[b - 1];
}

__global__ __launch_bounds__(256) void perm_k(const int* __restrict__ dst,
                                              int* __restrict__ off2,
                                              int* __restrict__ perm,
                                              int* __restrict__ dsts) {
  int e = blockIdx.x * 256 + threadIdx.x;
  if (e >= NE) return;
  int d = dst[e];
  int p = atomicAdd(&off2[d], 1);
  perm[p] = e;
  dsts[p] = d;
}

// ---------------- fused edge-MLP layer 1 (bf16 MFMA, 128-edge tiles) ----------
// [R12-verified configuration, unchanged]

__global__ __launch_bounds__(512, 6) void edge_mlp1(
    const short* __restrict__ nfb, const float* __restrict__ ef,
    const int* __restrict__ src, const int* __restrict__ perm,
    const int* __restrict__ dsts, const float* __restrict__ invn1,
    const float* __restrict__ We1, const float* __restrict__ be1,
    const short* __restrict__ WaT, const float* __restrict__ ba,
    const short* __restrict__ WbT, const float* __restrict__ bbv,
    float* __restrict__ s1)
{
  __shared__ __align__(16) short Ms[128 * 136];  // 34816 B (M / T / R reuse)
  __shared__ int dse[128];
  __shared__ int sse[128];
  __shared__ float2 efs[128];
  const int t = threadIdx.x;
  const int e0 = swz8(blockIdx.x, NWGE1) * 128;
  const int lane = t & 63, wv = t >> 6;

  if (t < 128) {
    const int pe = perm[e0 + t];
    dse[t] = dsts[e0 + t];
    sse[t] = src[pe];
    efs[t] = *(const float2*)&ef[2 * pe];
  }
  __syncthreads();

  // ---- row pass: 16 edges/wave in TWO 8-pair chunks (16 prefetch VGPRs) ----
  {
    const int k2 = lane * 2;
    const float wA0 = We1[k2],       wA1 = We1[k2 + 1];
    const float wB0 = We1[128 + k2], wB1 = We1[128 + k2 + 1];
    const float bE0 = be1[k2],       bE1 = be1[k2 + 1];
#pragma unroll
    for (int ch = 0; ch < 2; ++ch) {
      bf2v hbv[8], dbv[8];
#pragma unroll
      for (int i = 0; i < 8; ++i) {
        const int e = wv * 16 + ch * 8 + i;
        hbv[i] = *(const bf2v*)&nfb[(size_t)sse[e] * 128 + k2];  // coalesced
        dbv[i] = *(const bf2v*)&nfb[(size_t)dse[e] * 128 + k2];
      }
#pragma unroll
      for (int i = 0; i < 8; ++i) {
        const int e = wv * 16 + ch * 8 + i;
        const int s = sse[e];
        const int d = dse[e];
        const float h0 = b2f(hbv[i][0]), h1v = b2f(hbv[i][1]);
        const float g0 = b2f(dbv[i][0]), g1 = b2f(dbv[i][1]);
        float sd = fmaf(h0, g0, h1v * g1);
#pragma unroll
        for (int o = 32; o >= 1; o >>= 1) sd += __shfl_xor(sd, o);
        const float c = sd * invn1[s] * invn1[d];
        const float2 f01 = efs[e];
        const float w0 = fmaf(f01.x, wA0, fmaf(f01.y, wB0, bE0));
        const float w1 = fmaf(f01.x, wA1, fmaf(f01.y, wB1, bE1));
        bf2v pk;
        pk[0] = f2b(c * w0 * h0);
        pk[1] = f2b(c * w1 * h1v);
        *(bf2v*)&Ms[e * 136 + k2] = pk;
      }
    }
  }
  __syncthreads();

  const int lr = lane & 15;
  const int lq = lane >> 4;
  const int n0 = wv * 16;           // 8 waves x 16 n = 128

  f4 acc[8];
#pragma unroll
  for (int b = 0; b < 8; ++b) acc[b] = (f4)0.f;

  // ---- stage 1: K = 128 (B-groups in halves of 4 to cap reg peak) ----
#pragma unroll
  for (int kc = 0; kc < 128; kc += 32) {
    bf8 aF = *(const bf8*)&WaT[(size_t)(n0 + lr) * 128 + kc + lq * 8];
#pragma unroll
    for (int hf = 0; hf < 2; ++hf) {
      bf8 bF[4];
#pragma unroll
      for (int b2 = 0; b2 < 4; ++b2)
        bF[b2] = *(const bf8*)&Ms[((hf * 4 + b2) * 16 + lr) * 136 + kc + lq * 8];
      __builtin_amdgcn_s_setprio(1);
#pragma unroll
      for (int b2 = 0; b2 < 4; ++b2)
        acc[hf * 4 + b2] =
            __builtin_amdgcn_mfma_f32_16x16x32_bf16(aF, bF[b2], acc[hf * 4 + b2], 0, 0, 0);
      __builtin_amdgcn_s_setprio(0);
    }
  }
  __syncthreads();

  // T[e][n] = relu(acc + ba[n]) -> Ms
  {
    const int n = n0 + lq * 4;
    f4 bb = *(const f4*)&ba[n];
#pragma unroll
    for (int b = 0; b < 8; ++b) {
      bf4v pk;
#pragma unroll
      for (int r = 0; r < 4; ++r) pk[r] = f2b(fmaxf(acc[b][r] + bb[r], 0.f));
      *(bf4v*)&Ms[(b * 16 + lr) * 136 + n] = pk;
    }
  }
  __syncthreads();

  // ---- stage 2: K = 128 ----
#pragma unroll
  for (int b = 0; b < 8; ++b) acc[b] = (f4)0.f;
#pragma unroll
  for (int kc = 0; kc < 128; kc += 32) {
    bf8 aF = *(const bf8*)&WbT[(size_t)(n0 + lr) * 128 + kc + lq * 8];
#pragma unroll
    for (int hf = 0; hf < 2; ++hf) {
      bf8 bF[4];
#pragma unroll
      for (int b2 = 0; b2 < 4; ++b2)
        bF[b2] = *(const bf8*)&Ms[((hf * 4 + b2) * 16 + lr) * 136 + kc + lq * 8];
      __builtin_amdgcn_s_setprio(1);
#pragma unroll
      for (int b2 = 0; b2 < 4; ++b2)
        acc[hf * 4 + b2] =
            __builtin_amdgcn_mfma_f32_16x16x32_bf16(aF, bF[b2], acc[hf * 4 + b2], 0, 0, 0);
      __builtin_amdgcn_s_setprio(0);
    }
  }
  __syncthreads();   // all waves done reading Ms before R overwrite

  // R[e][n] = relu(acc + bb[n]) -> Ms (bf16; sums still accumulate in fp32)
  {
    const int n = n0 + lq * 4;
    f4 bb = *(const f4*)&bbv[n];
#pragma unroll
    for (int b = 0; b < 8; ++b) {
      bf4v pk;
#pragma unroll
      for (int r = 0; r < 4; ++r) pk[r] = f2b(fmaxf(acc[b][r] + bb[r], 0.f));
      *(bf4v*)&Ms[(b * 16 + lr) * 136 + n] = pk;
    }
  }
  __syncthreads();

  // segmented reduce over sorted dst (4 walkers x 32 edges per feature)
  {
    const int f = t & 127;
    const int eb = (t >> 7) * 32;
    float run = 0.f;
    int pd = dse[eb];
#pragma unroll 4
    for (int e = eb; e < eb + 32; ++e) {
      const int d = dse[e];         // wave-uniform
      if (d != pd) {
        atomicAdd(&s1[(size_t)pd * 128 + f], run);
        run = 0.f;
        pd = d;
      }
      run += b2f(Ms[e * 136 + f]);
    }
    atomicAdd(&s1[(size_t)pd * 128 + f], run);
  }
}

// ---------------- fused edge-MLP layer 2 (bf16 MFMA, 256-edge tiles) ----------
// 512 threads / 8 waves per 256-edge block; each wave owns a 32-wide n-slice
// and 32 edges of row-pass work. acc[2][16]=128 AGPR under (512,2)=256 regs;
// stage loops process B-groups in halves of 8 (transient <=36 VGPR); row pass
// in 4 chunks of 8 pairs. 1 block/CU (LDS ~138 KB); all barriers intra-CU.
// Fixed per-block cost halves again vs 128-edge; weight L2 traffic/edge halves.

__global__ __launch_bounds__(512, 2) void edge_mlp2(
    const short* __restrict__ h1b, const float* __restrict__ ef,
    const int* __restrict__ src, const int* __restrict__ perm,
    const int* __restrict__ dsts, const float* __restrict__ invn2,
    const float* __restrict__ We1, const float* __restrict__ be1,
    const short* __restrict__ We2T, const float* __restrict__ be2,
    const short* __restrict__ WaT, const float* __restrict__ ba,
    const short* __restrict__ WbT, const float* __restrict__ bbv,
    float* __restrict__ s2)
{
  __shared__ __align__(16) short U[256 * 264];   // 135168 B: Ws then M2s
  __shared__ int dse[256];
  __shared__ int pes[256];
  __shared__ int sse[256];
  short* Ws  = U;                                // 256 x 136
  short* M2s = U;                                // 256 x 264
  const int t = threadIdx.x;
  const int e0 = swz8(blockIdx.x, NWGE2) * 256;
  const int lane = t & 63, wv = t >> 6;          // wv in 0..7
  const int lr = lane & 15;
  const int lq = lane >> 4;
  const int n0 = wv * 32;                        // 8 waves x 32 n = 256

  if (t < 256) {
    const int pe = perm[e0 + t];
    pes[t] = pe;
    dse[t] = dsts[e0 + t];
    sse[t] = src[pe];
  }
  __syncthreads();

  // ---- build relu(w1) tile (bf16) into Ws: 256 edges x 2 threads ----
  {
    const int e = t >> 1;
    const int kb = (t & 1) * 64;
    const int pe = pes[e];
    const float f0 = ef[2 * pe], f1 = ef[2 * pe + 1];
#pragma unroll
    for (int j = 0; j < 8; ++j) {
      const int k = kb + j * 8;
      f4 wa0 = *(const f4*)&We1[k];
      f4 wa1 = *(const f4*)&We1[k + 4];
      f4 wb0 = *(const f4*)&We1[128 + k];
      f4 wb1 = *(const f4*)&We1[128 + k + 4];
      f4 b0 = *(const f4*)&be1[k];
      f4 b1 = *(const f4*)&be1[k + 4];
      bf8 pk;
#pragma unroll
      for (int x = 0; x < 4; ++x) {
        pk[x]     = f2b(fmaxf(fmaf(f0, wa0[x], fmaf(f1, wb0[x], b0[x])), 0.f));
        pk[x + 4] = f2b(fmaxf(fmaf(f0, wa1[x], fmaf(f1, wb1[x], b1[x])), 0.f));
      }
      *(bf8*)&Ws[e * 136 + k] = pk;
    }
  }
  __syncthreads();

  f4 acc[2][16];
#pragma unroll
  for (int a = 0; a < 2; ++a)
#pragma unroll
    for (int b = 0; b < 16; ++b) acc[a][b] = (f4)0.f;

  // ---- stage B: K = 128 (reads Ws; B-groups in halves of 8) ----
#pragma unroll
  for (int kc = 0; kc < 128; kc += 32) {
    bf8 aF[2];
#pragma unroll
    for (int a = 0; a < 2; ++a)
      aF[a] = *(const bf8*)&We2T[(size_t)(n0 + a * 16 + lr) * 128 + kc + lq * 8];
#pragma unroll
    for (int hf = 0; hf < 2; ++hf) {
      bf8 bF[8];
#pragma unroll
      for (int b2 = 0; b2 < 8; ++b2)
        bF[b2] = *(const bf8*)&Ws[((hf * 8 + b2) * 16 + lr) * 136 + kc + lq * 8];
      __builtin_amdgcn_s_setprio(1);
#pragma unroll
      for (int a = 0; a < 2; ++a)
#pragma unroll
        for (int b2 = 0; b2 < 8; ++b2)
          acc[a][hf * 8 + b2] = __builtin_amdgcn_mfma_f32_16x16x32_bf16(
              aF[a], bF[b2], acc[a][hf * 8 + b2], 0, 0, 0);
      __builtin_amdgcn_s_setprio(0);
    }
  }
  __syncthreads();   // Ws dead; M2s region may now be written

  // w2[e][n] = acc + be2[n] -> M2s (bf16, no cos/h yet)
#pragma unroll
  for (int b = 0; b < 16; ++b) {
#pragma unroll
    for (int a = 0; a < 2; ++a) {
      const int n = n0 + a * 16 + lq * 4;
      f4 bb = *(const f4*)&be2[n];
      bf4v pk;
#pragma unroll
      for (int r = 0; r < 4; ++r) pk[r] = f2b(acc[a][b][r] + bb[r]);
      *(bf4v*)&M2s[(b * 16 + lr) * 264 + n] = pk;
    }
  }
  __syncthreads();

  // ---- row pass: 32 edges/wave in FOUR 8-pair chunks (32 prefetch VGPRs) ----
  {
    const int k4 = lane * 4;
#pragma unroll
    for (int ch = 0; ch < 4; ++ch) {
      bf4v hsv[8], hdv[8];
#pragma unroll
      for (int i = 0; i < 8; ++i) {
        const int e = wv * 32 + ch * 8 + i;
        hsv[i] = *(const bf4v*)&h1b[(size_t)sse[e] * 256 + k4];  // coalesced
        hdv[i] = *(const bf4v*)&h1b[(size_t)dse[e] * 256 + k4];
      }
#pragma unroll
      for (int i = 0; i < 8; ++i) {
        const int e = wv * 32 + ch * 8 + i;
        const int s = sse[e];
        const int d = dse[e];
        f4 hs = b2f4(hsv[i]);
        f4 hd = b2f4(hdv[i]);
        float sd = 0.f;
#pragma unroll
        for (int r = 0; r < 4; ++r) sd = fmaf(hs[r], hd[r], sd);
#pragma unroll
        for (int o = 32; o >= 1; o >>= 1) sd += __shfl_xor(sd, o);
        const float c = sd * invn2[s] * invn2[d];
        f4 w = b2f4(*(const bf4v*)&M2s[e * 264 + k4]);
        bf4v pk;
#pragma unroll
        for (int r = 0; r < 4; ++r) pk[r] = f2b(w[r] * c * hs[r]);
        *(bf4v*)&M2s[e * 264 + k4] = pk;
      }
    }
  }
  __syncthreads();

  // ---- stage C: K = 256, relu (B-groups in halves of 8) ----
#pragma unroll
  for (int a = 0; a < 2; ++a)
#pragma unroll
    for (int b = 0; b < 16; ++b) acc[a][b] = (f4)0.f;
  for (int kc = 0; kc < 256; kc += 32) {
    bf8 aF[2];
#pragma unroll
    for (int a = 0; a < 2; ++a)
      aF[a] = *(const bf8*)&WaT[(size_t)(n0 + a * 16 + lr) * 256 + kc + lq * 8];
#pragma unroll
    for (int hf = 0; hf < 2; ++hf) {
      bf8 bF[8];
#pragma unroll
      for (int b2 = 0; b2 < 8; ++b2)
        bF[b2] = *(const bf8*)&M2s[((hf * 8 + b2) * 16 + lr) * 264 + kc + lq * 8];
      __builtin_amdgcn_s_setprio(1);
#pragma unroll
      for (int a = 0; a < 2; ++a)
#pragma unroll
        for (int b2 = 0; b2 < 8; ++b2)
          acc[a][hf * 8 + b2] = __builtin_amdgcn_mfma_f32_16x16x32_bf16(
              aF[a], bF[b2], acc[a][hf * 8 + b2], 0, 0, 0);
      __builtin_amdgcn_s_setprio(0);
    }
  }
  __syncthreads();

#pragma unroll
  for (int a = 0; a < 2; ++a) {
    const int n = n0 + a * 16 + lq * 4;
    f4 bb = *(const f4*)&ba[n];
#pragma unroll
    for (int b = 0; b < 16; ++b) {
      bf4v pk;
#pragma unroll
      for (int r = 0; r < 4; ++r) pk[r] = f2b(fmaxf(acc[a][b][r] + bb[r], 0.f));
      *(bf4v*)&M2s[(b * 16 + lr) * 264 + n] = pk;
    }
  }
  __syncthreads();

  // ---- stage D: K = 256 (B-groups in halves of 8) ----
#pragma unroll
  for (int a = 0; a < 2; ++a)
#pragma unroll
    for (int b = 0; b < 16; ++b) acc[a][b] = (f4)0.f;
  for (int kc = 0; kc < 256; kc += 32) {
    bf8 aF[2];
#pragma unroll
    for (int a = 0; a < 2; ++a)
      aF[a] = *(const bf8*)&WbT[(size_t)(n0 + a * 16 + lr) * 256 + kc + lq * 8];
#pragma unroll
    for (int hf = 0; hf < 2; ++hf) {
      bf8 bF[8];
#pragma unroll
      for (int b2 = 0; b2 < 8; ++b2)
        bF[b2] = *(const bf8*)&M2s[((hf * 8 + b2) * 16 + lr) * 264 + kc + lq * 8];
      __builtin_amdgcn_s_setprio(1);
#pragma unroll
      for (int a = 0; a < 2; ++a)
#pragma unroll
        for (int b2 = 0; b2 < 8; ++b2)
          acc[a][hf * 8 + b2] = __builtin_amdgcn_mfma_f32_16x16x32_bf16(
              aF[a], bF[b2], acc[a][hf * 8 + b2], 0, 0, 0);
      __builtin_amdgcn_s_setprio(0);
    }
  }
  __syncthreads();  // all waves done reading M2s before fp32 reuse

  // epilogue: two n-halves; write relu+bias fp32 into RF (=M2s), seg-reduce
  float* RF = (float*)M2s;   // 256 x 132 fp32 = 135168 B (exactly M2s)
#pragma unroll
  for (int h = 0; h < 2; ++h) {
    if ((wv >> 2) == h) {    // waves 0-3 hold n 0..127, waves 4-7 hold 128..255
#pragma unroll
      for (int a = 0; a < 2; ++a) {
        const int n = n0 + a * 16 + lq * 4;
        f4 bb = *(const f4*)&bbv[n];
#pragma unroll
        for (int b = 0; b < 16; ++b) {
          f4 v;
#pragma unroll
          for (int r = 0; r < 4; ++r) v[r] = fmaxf(acc[a][b][r] + bb[r], 0.f);
          *(f4*)&RF[(b * 16 + lr) * 132 + (n - h * 128)] = v;
        }
      }
    }
    __syncthreads();
    {
      const int f = t & 127;
      const int eb = (t >> 7) * 64;
      float run = 0.f;
      int pd = dse[eb];
#pragma unroll 4
      for (int e = eb; e < eb + 64; ++e) {
        const int d = dse[e];        // wave-uniform
        if (d != pd) {
          atomicAdd(&s2[(size_t)pd * 256 + h * 128 + f], run);
          run = 0.f;
          pd = d;
        }
        run += RF[e * 132 + f];
      }
      atomicAdd(&s2[(size_t)pd * 256 + h * 128 + f], run);
    }
    __syncthreads();
  }
}

// ---------------- node linear 1 (bf16 MFMA) -> h1b (bf16) ---------------------

__global__ __launch_bounds__(256, 3) void h1m_k(
    const float* __restrict__ nf, const float* __restrict__ s1,
    const int* __restrict__ cnt, const short* __restrict__ Wl1T,
    const float* __restrict__ bl1, short* __restrict__ h1b)
{
  __shared__ __align__(16) short As[64 * 264];
  const int t = threadIdx.x;
  const int v0 = blockIdx.x * 64;

  {
    const int row = t >> 2;
    const int kb = (t & 3) * 64;
    int gn = v0 + row;
    if (gn >= NN) gn = NN - 1;
    const float inv = 1.f / fmaxf((float)cnt[gn], 1.f);
#pragma unroll
    for (int j = 0; j < 64; j += 8) {
      const int k = kb + j;
      f4 x0, x1;
      if (k < 128) {
        x0 = *(const f4*)&nf[(size_t)gn * 128 + k];
        x1 = *(const f4*)&nf[(size_t)gn * 128 + k + 4];
      } else {
        x0 = *(const f4*)&s1[(size_t)gn * 128 + (k - 128)];
        x1 = *(const f4*)&s1[(size_t)gn * 128 + (k - 124)];
#pragma unroll
        for (int x = 0; x < 4; ++x) { x0[x] *= inv; x1[x] *= inv; }
      }
      bf8 pk;
#pragma unroll
      for (int x = 0; x < 4; ++x) { pk[x] = f2b(x0[x]); pk[x + 4] = f2b(x1[x]); }
      *(bf8*)&As[row * 264 + k] = pk;
    }
  }
  __syncthreads();

  const int lane = t & 63, wv = t >> 6;
  const int lr = lane & 15;
  const int lq = lane >> 4;
  const int n0 = wv * 64;

  f4 acc[4][4];
#pragma unroll
  for (int a = 0; a < 4; ++a)
#pragma unroll
    for (int b = 0; b < 4; ++b) acc[a][b] = (f4)0.f;

  for (int kc = 0; kc < 256; kc += 32) {
    bf8 aF[4], bF[4];
#pragma unroll
    for (int a = 0; a < 4; ++a)
      aF[a] = *(const bf8*)&Wl1T[(size_t)(n0 + a * 16 + lr) * 256 + kc + lq * 8];
#pragma unroll
    for (int b = 0; b < 4; ++b)
      bF[b] = *(const bf8*)&As[(b * 16 + lr) * 264 + kc + lq * 8];
#pragma unroll
    for (int a = 0; a < 4; ++a)
#pragma unroll
      for (int b = 0; b < 4; ++b)
        acc[a][b] = __builtin_amdgcn_mfma_f32_16x16x32_bf16(aF[a], bF[b], acc[a][b], 0, 0, 0);
  }

#pragma unroll
  for (int b = 0; b < 4; ++b) {
    const int gn = v0 + b * 16 + lr;
    if (gn >= NN) continue;
#pragma unroll
    for (int a = 0; a < 4; ++a) {
      const int n = n0 + a * 16 + lq * 4;
      f4 bb = *(const f4*)&bl1[n];
      bf4v pk;
      pk[0] = f2b(fmaxf(acc[a][b][0] + bb[0], 0.f));
      pk[1] = f2b(fmaxf(acc[a][b][1] + bb[1], 0.f));
      pk[2] = f2b(fmaxf(acc[a][b][2] + bb[2], 0.f));
      pk[3] = f2b(fmaxf(acc[a][b][3] + bb[3], 0.f));
      *(bf4v*)&h1b[(size_t)gn * 256 + n] = pk;
    }
  }
}

// ---------------- final linear: out = concat(h1b, s2/cnt) @ Wl2 + bl2 ---------

__global__ __launch_bounds__(256) void out_k(
    const short* __restrict__ h1b, const float* __restrict__ s2,
    const int* __restrict__ cnt, const float* __restrict__ Wl2,
    const float* __restrict__ bl2, float* __restrict__ out)
{
  __shared__ float A8[8][512];
  const int n0 = blockIdx.x * 8;
  const int tx = threadIdx.x;
  const int ty = threadIdx.y;
  const int t = ty * 32 + tx;
  const int row = t >> 5;
  const int k0 = (t & 31) * 16;
  const int n = n0 + row;
  const float inv = 1.0f / fmaxf((float)cnt[n], 1.0f);
#pragma unroll
  for (int i = 0; i < 16; i += 4) {
    int k = k0 + i;
    f4 v;
    if (k < 256) {
      v = b2f4(*(const bf4v*)&h1b[(size_t)n * 256 + k]);
    } else {
      v = *(const f4*)&s2[(size_t)n * 256 + (k - 256)];
      v[0] *= inv; v[1] *= inv; v[2] *= inv; v[3] *= inv;
    }
    *(f4*)&A8[row][k] = v;
  }
  __syncthreads();
  float acc = bl2[tx];
#pragma unroll 8
  for (int k = 0; k < 512; k++) acc = fmaf(A8[ty][k], Wl2[(size_t)k * 32 + tx], acc);
  out[(size_t)(n0 + ty) * 32 + tx] = acc;
}

// ---------------- launch ------------------------------------------------------

extern "C" void kernel_launch(void* const* d_in, const int* in_sizes, int n_in,
                              void* d_out, int out_size, void* d_ws, size_t ws_size,
                              hipStream_t stream) {
  const float* nf   = (const float*)d_in[0];
  const float* ef   = (const float*)d_in[1];
  const int*   src  = (const int*)d_in[2];
  const int*   dst  = (const int*)d_in[3];
  const float* We1  = (const float*)d_in[4];
  const float* be1  = (const float*)d_in[5];
  const float* Wr1a = (const float*)d_in[6];
  const float* br1a = (const float*)d_in[7];
  const float* Wr1b = (const float*)d_in[8];
  const float* br1b = (const float*)d_in[9];
  const float* Wl1  = (const float*)d_in[10];
  const float* bl1  = (const float*)d_in[11];
  const float* We2  = (const float*)d_in[12];
  const float* be2  = (const float*)d_in[13];
  const float* Wr2a = (const float*)d_in[14];
  const float* br2a = (const float*)d_in[15];
  const float* Wr2b = (const float*)d_in[16];
  const float* br2b = (const float*)d_in[17];
  const float* Wl2  = (const float*)d_in[18];
  const float* bl2  = (const float*)d_in[19];

  float* ws = (float*)d_ws;
  float* s1   = ws;                             // N*128 f
  float* s2   = s1 + (size_t)NN * 128;          // N*256 f
  int*   cnt  = (int*)(s2 + (size_t)NN * 256);  // N
  short* h1b  = (short*)(cnt + NN);             // N*256 bf16
  short* nfb  = h1b + (size_t)NN * 256;         // N*128 bf16
  short* WaT1 = nfb + (size_t)NN * 128;         // 128*128 bf16
  short* WbT1 = WaT1 + 128 * 128;               // 128*128
  short* We2T = WbT1 + 128 * 128;               // 256*128
  short* WaT2 = We2T + 256 * 128;               // 256*256
  short* WbT2 = WaT2 + 256 * 256;               // 256*256
  short* Wl1T = WbT2 + 256 * 256;               // 256*256
  int*   off2 = (int*)(Wl1T + 256 * 256);       // N
  int*   perm = off2 + NN;                      // E
  int*   dsts = perm + NE;                      // E
  float* invn1 = (float*)(dsts + NE);           // N
  float* invn2 = invn1 + NN;                    // N
  int*   bsum  = (int*)(invn2 + NN);            // 64

  size_t need = ((size_t)NN * 128 + (size_t)NN * 256 + NN) * 4 +
                ((size_t)NN * 256 + (size_t)NN * 128 +
                 (size_t)128 * 128 * 2 + (size_t)256 * 128 +
                 (size_t)256 * 256 * 3) * 2 +
                ((size_t)NN + 2 * (size_t)NE + 2 * (size_t)NN) * 4 + 64 * 4;
  if (ws_size < need) return;

  // zero s1, s2, cnt (contiguous) first: prep_k accumulates cnt
  hipMemsetAsync(s1, 0, ((size_t)NN * 128 + (size_t)NN * 256 + NN) * 4, stream);

  // merged: 6 weight transposes + nf->bf16 + degree count
  prep_k<<<10399, 256, 0, stream>>>(Wr1a, Wr1b, We2, Wr2a, Wr2b, Wl1,
                                    WaT1, WbT1, We2T, WaT2, WbT2, Wl1T,
                                    nf, nfb, dst, cnt);
  norm1_k<<<(NN + 3) / 4, 256, 0, stream>>>(nfb, invn1);

  // hierarchical counting-sort scan (49 chunks of 1024)
  const int nb = (NN + 1023) / 1024;
  scanA_k<<<nb, 1024, 0, stream>>>(cnt, off2, bsum);
  scanB_k<<<1, 64, 0, stream>>>(bsum, nb);
  scanC_k<<<(NN + 255) / 256, 256, 0, stream>>>(off2, bsum);
  perm_k<<<NE / 256, 256, 0, stream>>>(dst, off2, perm, dsts);

  edge_mlp1<<<NWGE1, 512, 0, stream>>>(nfb, ef, src, perm, dsts, invn1,
                                       We1, be1, WaT1, br1a, WbT1, br1b, s1);

  h1m_k<<<(NN + 63) / 64, 256, 0, stream>>>(nf, s1, cnt, Wl1T, bl1, h1b);
  norm2_k<<<(NN + 3) / 4, 256, 0, stream>>>(h1b, invn2);

  edge_mlp2<<<NWGE2, 512, 0, stream>>>(h1b, ef, src, perm, dsts, invn2,
                                       We1, be1, We2T, be2, WaT2, br2a,
                                       WbT2, br2b, s2);

  out_k<<<NN / 8, dim3(32, 8), 0, stream>>>(h1b, s2, cnt, Wl2, bl2, (float*)d_out);
}

// Round 15
// 1056.143 us; speedup vs baseline: 1.0531x; 1.0531x over previous
//
#include <hip/hip_runtime.h>
#include <math.h>

#define NN 50000
#define NE 800000
#define NWGE1 (NE / 128)  // 6250 edge blocks (mlp1)
#define NWGE2 (NE / 128)  // 6250 edge blocks (mlp2)

typedef short bf8 __attribute__((ext_vector_type(8)));
typedef short bf4v __attribute__((ext_vector_type(4)));
typedef short bf2v __attribute__((ext_vector_type(2)));
typedef float f4 __attribute__((ext_vector_type(4)));

// float -> bf16 bits, round-to-nearest-even (values are finite)
__device__ __forceinline__ short f2b(float f) {
  unsigned int u = __float_as_uint(f);
  unsigned int r = (u + 0x7FFFu + ((u >> 16) & 1u)) >> 16;
  return (short)(unsigned short)r;
}
__device__ __forceinline__ float b2f(short s) {
  return __uint_as_float(((unsigned int)(unsigned short)s) << 16);
}
__device__ __forceinline__ f4 b2f4(bf4v p) {
  f4 v;
  v[0] = b2f(p[0]); v[1] = b2f(p[1]); v[2] = b2f(p[2]); v[3] = b2f(p[3]);
  return v;
}

// bijective XCD-aware swizzle (8 XCDs): blocks on the same XCD get a
// CONTIGUOUS range of dst-sorted edge chunks -> dst gather/atomics localize.
__device__ __forceinline__ int swz8(int b, int nwg) {
  const int q = nwg >> 3, r = nwg & 7;
  const int x = b & 7, o = b >> 3;
  return (x < r ? x * (q + 1) : r * (q + 1) + (x - r) * q) + o;
}

// ---------------- merged preprocessing: 6 transposes + nf convert + degree ----
// blocks [0,1024): weight transpose+cvt; [1024,7274): nf cvt; [7274,10399): cnt

__global__ __launch_bounds__(256) void prep_k(
    const float* __restrict__ Wr1a, const float* __restrict__ Wr1b,
    const float* __restrict__ We2,  const float* __restrict__ Wr2a,
    const float* __restrict__ Wr2b, const float* __restrict__ Wl1,
    short* __restrict__ WaT1, short* __restrict__ WbT1,
    short* __restrict__ We2T, short* __restrict__ WaT2,
    short* __restrict__ WbT2, short* __restrict__ Wl1T,
    const float* __restrict__ nf, short* __restrict__ nfb,
    const int* __restrict__ dst, int* __restrict__ cnt)
{
  const int b = blockIdx.x;
  if (b < 1024) {
    const float* in; short* out; int K, N, bb;
    if (b < 64)       { in = Wr1a; out = WaT1; K = 128; N = 128; bb = b; }
    else if (b < 128) { in = Wr1b; out = WbT1; K = 128; N = 128; bb = b - 64; }
    else if (b < 256) { in = We2;  out = We2T; K = 128; N = 256; bb = b - 128; }
    else if (b < 512) { in = Wr2a; out = WaT2; K = 256; N = 256; bb = b - 256; }
    else if (b < 768) { in = Wr2b; out = WbT2; K = 256; N = 256; bb = b - 512; }
    else              { in = Wl1;  out = Wl1T; K = 256; N = 256; bb = b - 768; }
    const int i = bb * 256 + threadIdx.x;
    if (i < K * N) {
      const int n = i / K, k = i - n * K;
      out[i] = f2b(in[(size_t)k * N + n]);
    }
  } else if (b < 7274) {
    const int i = (b - 1024) * 256 + threadIdx.x;   // i < NN*128/4 = 1.6M exactly
    f4 v = *(const f4*)&nf[(size_t)i * 4];
    bf4v p;
    p[0] = f2b(v[0]); p[1] = f2b(v[1]); p[2] = f2b(v[2]); p[3] = f2b(v[3]);
    *(bf4v*)&nfb[(size_t)i * 4] = p;
  } else {
    const int e = (b - 7274) * 256 + threadIdx.x;   // e < NE exactly
    atomicAdd(&cnt[dst[e]], 1);
  }
}

// ---------------- per-node inverse norms --------------------------------------
__global__ __launch_bounds__(256) void norm1_k(const short* __restrict__ nfb,
                                               float* __restrict__ invn) {
  const int node = blockIdx.x * 4 + (threadIdx.x >> 6);
  if (node >= NN) return;
  const int lane = threadIdx.x & 63;
  bf2v hb = *(const bf2v*)&nfb[(size_t)node * 128 + lane * 2];
  float h0 = b2f(hb[0]), h1v = b2f(hb[1]);
  float ss = fmaf(h0, h0, h1v * h1v);
#pragma unroll
  for (int o = 32; o >= 1; o >>= 1) ss += __shfl_xor(ss, o);
  if (lane == 0) invn[node] = 1.f / fmaxf(sqrtf(ss), 1e-12f);
}

__global__ __launch_bounds__(256) void norm2_k(const short* __restrict__ h1b,
                                               float* __restrict__ invn) {
  const int node = blockIdx.x * 4 + (threadIdx.x >> 6);
  if (node >= NN) return;
  const int lane = threadIdx.x & 63;
  f4 h = b2f4(*(const bf4v*)&h1b[(size_t)node * 256 + lane * 4]);
  float ss = 0.f;
#pragma unroll
  for (int r = 0; r < 4; ++r) ss = fmaf(h[r], h[r], ss);
#pragma unroll
  for (int o = 32; o >= 1; o >>= 1) ss += __shfl_xor(ss, o);
  if (lane == 0) invn[node] = 1.f / fmaxf(sqrtf(ss), 1e-12f);
}

// ---------------- hierarchical counting-sort scan -----------------------------

__global__ __launch_bounds__(1024) void scanA_k(const int* __restrict__ cnt,
                                                int* __restrict__ off2,
                                                int* __restrict__ bsum) {
  __shared__ int buf[1024];
  const int t = threadIdx.x;
  const int i = blockIdx.x * 1024 + t;
  const int v = (i < NN) ? cnt[i] : 0;
  buf[t] = v;
  __syncthreads();
#pragma unroll
  for (int o = 1; o < 1024; o <<= 1) {
    int x = (t >= o) ? buf[t - o] : 0;
    __syncthreads();
    buf[t] += x;
    __syncthreads();
  }
  if (i < NN) off2[i] = buf[t] - v;
  if (t == 1023) bsum[blockIdx.x] = buf[t];
}

__global__ __launch_bounds__(64) void scanB_k(int* __restrict__ bsum, int nb) {
  const int t = threadIdx.x;
  int v = (t < nb) ? bsum[t] : 0;
#pragma unroll
  for (int o = 1; o < 64; o <<= 1) {
    int x = __shfl_up(v, o);
    if (t >= o) v += x;
  }
  if (t < nb) bsum[t] = v;   // inclusive totals
}

__global__ __launch_bounds__(256) void scanC_k(int* __restrict__ off2,
                                               const int* __restrict__ bsum) {
  const int i = blockIdx.x * 256 + threadIdx.x;
  if (i >= NN) return;
  const int b = i >> 10;
  if (b) off2[i] += bsum[b - 1];
}

__global__ __launch_bounds__(256) void perm_k(const int* __restrict__ dst,
                                              int* __restrict__ off2,
                                              int* __restrict__ perm,
                                              int* __restrict__ dsts) {
  int e = blockIdx.x * 256 + threadIdx.x;
  if (e >= NE) return;
  int d = dst[e];
  int p = atomicAdd(&off2[d], 1);
  perm[p] = e;
  dsts[p] = d;
}

// ---------------- fused edge-MLP layer 1 (bf16 MFMA, 128-edge tiles) ----------
// [R12-verified configuration, unchanged]

__global__ __launch_bounds__(512, 6) void edge_mlp1(
    const short* __restrict__ nfb, const float* __restrict__ ef,
    const int* __restrict__ src, const int* __restrict__ perm,
    const int* __restrict__ dsts, const float* __restrict__ invn1,
    const float* __restrict__ We1, const float* __restrict__ be1,
    const short* __restrict__ WaT, const float* __restrict__ ba,
    const short* __restrict__ WbT, const float* __restrict__ bbv,
    float* __restrict__ s1)
{
  __shared__ __align__(16) short Ms[128 * 136];  // 34816 B (M / T / R reuse)
  __shared__ int dse[128];
  __shared__ int sse[128];
  __shared__ float2 efs[128];
  const int t = threadIdx.x;
  const int e0 = swz8(blockIdx.x, NWGE1) * 128;
  const int lane = t & 63, wv = t >> 6;

  if (t < 128) {
    const int pe = perm[e0 + t];
    dse[t] = dsts[e0 + t];
    sse[t] = src[pe];
    efs[t] = *(const float2*)&ef[2 * pe];
  }
  __syncthreads();

  // ---- row pass: 16 edges/wave in TWO 8-pair chunks (16 prefetch VGPRs) ----
  {
    const int k2 = lane * 2;
    const float wA0 = We1[k2],       wA1 = We1[k2 + 1];
    const float wB0 = We1[128 + k2], wB1 = We1[128 + k2 + 1];
    const float bE0 = be1[k2],       bE1 = be1[k2 + 1];
#pragma unroll
    for (int ch = 0; ch < 2; ++ch) {
      bf2v hbv[8], dbv[8];
#pragma unroll
      for (int i = 0; i < 8; ++i) {
        const int e = wv * 16 + ch * 8 + i;
        hbv[i] = *(const bf2v*)&nfb[(size_t)sse[e] * 128 + k2];  // coalesced
        dbv[i] = *(const bf2v*)&nfb[(size_t)dse[e] * 128 + k2];
      }
#pragma unroll
      for (int i = 0; i < 8; ++i) {
        const int e = wv * 16 + ch * 8 + i;
        const int s = sse[e];
        const int d = dse[e];
        const float h0 = b2f(hbv[i][0]), h1v = b2f(hbv[i][1]);
        const float g0 = b2f(dbv[i][0]), g1 = b2f(dbv[i][1]);
        float sd = fmaf(h0, g0, h1v * g1);
#pragma unroll
        for (int o = 32; o >= 1; o >>= 1) sd += __shfl_xor(sd, o);
        const float c = sd * invn1[s] * invn1[d];
        const float2 f01 = efs[e];
        const float w0 = fmaf(f01.x, wA0, fmaf(f01.y, wB0, bE0));
        const float w1 = fmaf(f01.x, wA1, fmaf(f01.y, wB1, bE1));
        bf2v pk;
        pk[0] = f2b(c * w0 * h0);
        pk[1] = f2b(c * w1 * h1v);
        *(bf2v*)&Ms[e * 136 + k2] = pk;
      }
    }
  }
  __syncthreads();

  const int lr = lane & 15;
  const int lq = lane >> 4;
  const int n0 = wv * 16;           // 8 waves x 16 n = 128

  f4 acc[8];
#pragma unroll
  for (int b = 0; b < 8; ++b) acc[b] = (f4)0.f;

  // ---- stage 1: K = 128 (B-groups in halves of 4 to cap reg peak) ----
#pragma unroll
  for (int kc = 0; kc < 128; kc += 32) {
    bf8 aF = *(const bf8*)&WaT[(size_t)(n0 + lr) * 128 + kc + lq * 8];
#pragma unroll
    for (int hf = 0; hf < 2; ++hf) {
      bf8 bF[4];
#pragma unroll
      for (int b2 = 0; b2 < 4; ++b2)
        bF[b2] = *(const bf8*)&Ms[((hf * 4 + b2) * 16 + lr) * 136 + kc + lq * 8];
      __builtin_amdgcn_s_setprio(1);
#pragma unroll
      for (int b2 = 0; b2 < 4; ++b2)
        acc[hf * 4 + b2] =
            __builtin_amdgcn_mfma_f32_16x16x32_bf16(aF, bF[b2], acc[hf * 4 + b2], 0, 0, 0);
      __builtin_amdgcn_s_setprio(0);
    }
  }
  __syncthreads();

  // T[e][n] = relu(acc + ba[n]) -> Ms
  {
    const int n = n0 + lq * 4;
    f4 bb = *(const f4*)&ba[n];
#pragma unroll
    for (int b = 0; b < 8; ++b) {
      bf4v pk;
#pragma unroll
      for (int r = 0; r < 4; ++r) pk[r] = f2b(fmaxf(acc[b][r] + bb[r], 0.f));
      *(bf4v*)&Ms[(b * 16 + lr) * 136 + n] = pk;
    }
  }
  __syncthreads();

  // ---- stage 2: K = 128 ----
#pragma unroll
  for (int b = 0; b < 8; ++b) acc[b] = (f4)0.f;
#pragma unroll
  for (int kc = 0; kc < 128; kc += 32) {
    bf8 aF = *(const bf8*)&WbT[(size_t)(n0 + lr) * 128 + kc + lq * 8];
#pragma unroll
    for (int hf = 0; hf < 2; ++hf) {
      bf8 bF[4];
#pragma unroll
      for (int b2 = 0; b2 < 4; ++b2)
        bF[b2] = *(const bf8*)&Ms[((hf * 4 + b2) * 16 + lr) * 136 + kc + lq * 8];
      __builtin_amdgcn_s_setprio(1);
#pragma unroll
      for (int b2 = 0; b2 < 4; ++b2)
        acc[hf * 4 + b2] =
            __builtin_amdgcn_mfma_f32_16x16x32_bf16(aF, bF[b2], acc[hf * 4 + b2], 0, 0, 0);
      __builtin_amdgcn_s_setprio(0);
    }
  }
  __syncthreads();   // all waves done reading Ms before R overwrite

  // R[e][n] = relu(acc + bb[n]) -> Ms (bf16; sums still accumulate in fp32)
  {
    const int n = n0 + lq * 4;
    f4 bb = *(const f4*)&bbv[n];
#pragma unroll
    for (int b = 0; b < 8; ++b) {
      bf4v pk;
#pragma unroll
      for (int r = 0; r < 4; ++r) pk[r] = f2b(fmaxf(acc[b][r] + bb[r], 0.f));
      *(bf4v*)&Ms[(b * 16 + lr) * 136 + n] = pk;
    }
  }
  __syncthreads();

  // segmented reduce over sorted dst (4 walkers x 32 edges per feature)
  {
    const int f = t & 127;
    const int eb = (t >> 7) * 32;
    float run = 0.f;
    int pd = dse[eb];
#pragma unroll 4
    for (int e = eb; e < eb + 32; ++e) {
      const int d = dse[e];         // wave-uniform
      if (d != pd) {
        atomicAdd(&s1[(size_t)pd * 128 + f], run);
        run = 0.f;
        pd = d;
      }
      run += b2f(Ms[e * 136 + f]);
    }
    atomicAdd(&s1[(size_t)pd * 128 + f], run);
  }
}

// ---------------- fused edge-MLP layer 2 (bf16 MFMA, 128-edge tiles) ----------
// [R13-verified configuration: 128-edge tiles, 2 blocks/CU, unroll-2 C/D]

__global__ __launch_bounds__(512, 4) void edge_mlp2(
    const short* __restrict__ h1b, const float* __restrict__ ef,
    const int* __restrict__ src, const int* __restrict__ perm,
    const int* __restrict__ dsts, const float* __restrict__ invn2,
    const float* __restrict__ We1, const float* __restrict__ be1,
    const short* __restrict__ We2T, const float* __restrict__ be2,
    const short* __restrict__ WaT, const float* __restrict__ ba,
    const short* __restrict__ WbT, const float* __restrict__ bbv,
    float* __restrict__ s2)
{
  __shared__ __align__(16) short U[128 * 264];   // 67584 B: Ws then M2s
  __shared__ int dse[128];
  __shared__ int pes[128];
  __shared__ int sse[128];
  short* Ws  = U;                                // 128 x 136
  short* M2s = U;                                // 128 x 264
  const int t = threadIdx.x;
  const int e0 = swz8(blockIdx.x, NWGE2) * 128;
  const int lane = t & 63, wv = t >> 6;          // wv in 0..7
  const int lr = lane & 15;
  const int lq = lane >> 4;
  const int n0 = wv * 32;                        // 8 waves x 32 n = 256

  if (t < 128) {
    const int pe = perm[e0 + t];
    pes[t] = pe;
    dse[t] = dsts[e0 + t];
    sse[t] = src[pe];
  }
  __syncthreads();

  // ---- build relu(w1) tile (bf16) into Ws: 128 edges x 4 threads ----
  {
    const int e = t >> 2;
    const int kb = (t & 3) * 32;
    const int pe = pes[e];
    const float f0 = ef[2 * pe], f1 = ef[2 * pe + 1];
#pragma unroll
    for (int j = 0; j < 4; ++j) {
      const int k = kb + j * 8;
      f4 wa0 = *(const f4*)&We1[k];
      f4 wa1 = *(const f4*)&We1[k + 4];
      f4 wb0 = *(const f4*)&We1[128 + k];
      f4 wb1 = *(const f4*)&We1[128 + k + 4];
      f4 b0 = *(const f4*)&be1[k];
      f4 b1 = *(const f4*)&be1[k + 4];
      bf8 pk;
#pragma unroll
      for (int x = 0; x < 4; ++x) {
        pk[x]     = f2b(fmaxf(fmaf(f0, wa0[x], fmaf(f1, wb0[x], b0[x])), 0.f));
        pk[x + 4] = f2b(fmaxf(fmaf(f0, wa1[x], fmaf(f1, wb1[x], b1[x])), 0.f));
      }
      *(bf8*)&Ws[e * 136 + k] = pk;
    }
  }
  __syncthreads();

  f4 acc[2][8];
#pragma unroll
  for (int a = 0; a < 2; ++a)
#pragma unroll
    for (int b = 0; b < 8; ++b) acc[a][b] = (f4)0.f;

  // ---- stage B: K = 128 (reads Ws) ----
#pragma unroll
  for (int kc = 0; kc < 128; kc += 32) {
    bf8 aF[2], bF[8];
#pragma unroll
    for (int a = 0; a < 2; ++a)
      aF[a] = *(const bf8*)&We2T[(size_t)(n0 + a * 16 + lr) * 128 + kc + lq * 8];
#pragma unroll
    for (int b = 0; b < 8; ++b)
      bF[b] = *(const bf8*)&Ws[(b * 16 + lr) * 136 + kc + lq * 8];
    __builtin_amdgcn_s_setprio(1);
#pragma unroll
    for (int a = 0; a < 2; ++a)
#pragma unroll
      for (int b = 0; b < 8; ++b)
        acc[a][b] = __builtin_amdgcn_mfma_f32_16x16x32_bf16(aF[a], bF[b], acc[a][b], 0, 0, 0);
    __builtin_amdgcn_s_setprio(0);
  }
  __syncthreads();   // Ws dead; M2s region may now be written

  // w2[e][n] = acc + be2[n] -> M2s (bf16, no cos/h yet)
#pragma unroll
  for (int b = 0; b < 8; ++b) {
#pragma unroll
    for (int a = 0; a < 2; ++a) {
      const int n = n0 + a * 16 + lq * 4;
      f4 bb = *(const f4*)&be2[n];
      bf4v pk;
#pragma unroll
      for (int r = 0; r < 4; ++r) pk[r] = f2b(acc[a][b][r] + bb[r]);
      *(bf4v*)&M2s[(b * 16 + lr) * 264 + n] = pk;
    }
  }
  __syncthreads();

  // ---- row pass: 16 edges/wave in TWO 8-pair chunks (32 prefetch VGPRs) ----
  {
    const int k4 = lane * 4;
#pragma unroll
    for (int ch = 0; ch < 2; ++ch) {
      bf4v hsv[8], hdv[8];
#pragma unroll
      for (int i = 0; i < 8; ++i) {
        const int e = wv * 16 + ch * 8 + i;
        hsv[i] = *(const bf4v*)&h1b[(size_t)sse[e] * 256 + k4];  // coalesced
        hdv[i] = *(const bf4v*)&h1b[(size_t)dse[e] * 256 + k4];
      }
#pragma unroll
      for (int i = 0; i < 8; ++i) {
        const int e = wv * 16 + ch * 8 + i;
        const int s = sse[e];
        const int d = dse[e];
        f4 hs = b2f4(hsv[i]);
        f4 hd = b2f4(hdv[i]);
        float sd = 0.f;
#pragma unroll
        for (int r = 0; r < 4; ++r) sd = fmaf(hs[r], hd[r], sd);
#pragma unroll
        for (int o = 32; o >= 1; o >>= 1) sd += __shfl_xor(sd, o);
        const float c = sd * invn2[s] * invn2[d];
        f4 w = b2f4(*(const bf4v*)&M2s[e * 264 + k4]);
        bf4v pk;
#pragma unroll
        for (int r = 0; r < 4; ++r) pk[r] = f2b(w[r] * c * hs[r]);
        *(bf4v*)&M2s[e * 264 + k4] = pk;
      }
    }
  }
  __syncthreads();

  // ---- stage C: K = 256, relu (unroll 2: pipeline aF loads) ----
#pragma unroll
  for (int a = 0; a < 2; ++a)
#pragma unroll
    for (int b = 0; b < 8; ++b) acc[a][b] = (f4)0.f;
#pragma unroll 2
  for (int kc = 0; kc < 256; kc += 32) {
    bf8 aF[2], bF[8];
#pragma unroll
    for (int a = 0; a < 2; ++a)
      aF[a] = *(const bf8*)&WaT[(size_t)(n0 + a * 16 + lr) * 256 + kc + lq * 8];
#pragma unroll
    for (int b = 0; b < 8; ++b)
      bF[b] = *(const bf8*)&M2s[(b * 16 + lr) * 264 + kc + lq * 8];
    __builtin_amdgcn_s_setprio(1);
#pragma unroll
    for (int a = 0; a < 2; ++a)
#pragma unroll
      for (int b = 0; b < 8; ++b)
        acc[a][b] = __builtin_amdgcn_mfma_f32_16x16x32_bf16(aF[a], bF[b], acc[a][b], 0, 0, 0);
    __builtin_amdgcn_s_setprio(0);
  }
  __syncthreads();

#pragma unroll
  for (int a = 0; a < 2; ++a) {
    const int n = n0 + a * 16 + lq * 4;
    f4 bb = *(const f4*)&ba[n];
#pragma unroll
    for (int b = 0; b < 8; ++b) {
      bf4v pk;
#pragma unroll
      for (int r = 0; r < 4; ++r) pk[r] = f2b(fmaxf(acc[a][b][r] + bb[r], 0.f));
      *(bf4v*)&M2s[(b * 16 + lr) * 264 + n] = pk;
    }
  }
  __syncthreads();

  // ---- stage D: K = 256 (unroll 2: pipeline aF loads) ----
#pragma unroll
  for (int a = 0; a < 2; ++a)
#pragma unroll
    for (int b = 0; b < 8; ++b) acc[a][b] = (f4)0.f;
#pragma unroll 2
  for (int kc = 0; kc < 256; kc += 32) {
    bf8 aF[2], bF[8];
#pragma unroll
    for (int a = 0; a < 2; ++a)
      aF[a] = *(const bf8*)&WbT[(size_t)(n0 + a * 16 + lr) * 256 + kc + lq * 8];
#pragma unroll
    for (int b = 0; b < 8; ++b)
      bF[b] = *(const bf8*)&M2s[(b * 16 + lr) * 264 + kc + lq * 8];
    __builtin_amdgcn_s_setprio(1);
#pragma unroll
    for (int a = 0; a < 2; ++a)
#pragma unroll
      for (int b = 0; b < 8; ++b)
        acc[a][b] = __builtin_amdgcn_mfma_f32_16x16x32_bf16(aF[a], bF[b], acc[a][b], 0, 0, 0);
    __builtin_amdgcn_s_setprio(0);
  }
  __syncthreads();  // all waves done reading M2s before fp32 reuse

  // epilogue: two n-halves; write relu+bias fp32 into RF (=M2s), seg-reduce
  float* RF = (float*)M2s;   // 128 x 132 fp32 = 67584 B (exactly M2s)
#pragma unroll
  for (int h = 0; h < 2; ++h) {
    if ((wv >> 2) == h) {    // waves 0-3 hold n 0..127, waves 4-7 hold 128..255
#pragma unroll
      for (int a = 0; a < 2; ++a) {
        const int n = n0 + a * 16 + lq * 4;
        f4 bb = *(const f4*)&bbv[n];
#pragma unroll
        for (int b = 0; b < 8; ++b) {
          f4 v;
#pragma unroll
          for (int r = 0; r < 4; ++r) v[r] = fmaxf(acc[a][b][r] + bb[r], 0.f);
          *(f4*)&RF[(b * 16 + lr) * 132 + (n - h * 128)] = v;
        }
      }
    }
    __syncthreads();
    {
      const int f = t & 127;
      const int eb = (t >> 7) * 32;
      float run = 0.f;
      int pd = dse[eb];
#pragma unroll 4
      for (int e = eb; e < eb + 32; ++e) {
        const int d = dse[e];        // wave-uniform
        if (d != pd) {
          atomicAdd(&s2[(size_t)pd * 256 + h * 128 + f], run);
          run = 0.f;
          pd = d;
        }
        run += RF[e * 132 + f];
      }
      atomicAdd(&s2[(size_t)pd * 256 + h * 128 + f], run);
    }
    __syncthreads();
  }
}

// ---------------- node linear 1 (bf16 MFMA) -> h1b (bf16) ---------------------

__global__ __launch_bounds__(256, 3) void h1m_k(
    const float* __restrict__ nf, const float* __restrict__ s1,
    const int* __restrict__ cnt, const short* __restrict__ Wl1T,
    const float* __restrict__ bl1, short* __restrict__ h1b)
{
  __shared__ __align__(16) short As[64 * 264];
  const int t = threadIdx.x;
  const int v0 = blockIdx.x * 64;

  {
    const int row = t >> 2;
    const int kb = (t & 3) * 64;
    int gn = v0 + row;
    if (gn >= NN) gn = NN - 1;
    const float inv = 1.f / fmaxf((float)cnt[gn], 1.f);
#pragma unroll
    for (int j = 0; j < 64; j += 8) {
      const int k = kb + j;
      f4 x0, x1;
      if (k < 128) {
        x0 = *(const f4*)&nf[(size_t)gn * 128 + k];
        x1 = *(const f4*)&nf[(size_t)gn * 128 + k + 4];
      } else {
        x0 = *(const f4*)&s1[(size_t)gn * 128 + (k - 128)];
        x1 = *(const f4*)&s1[(size_t)gn * 128 + (k - 124)];
#pragma unroll
        for (int x = 0; x < 4; ++x) { x0[x] *= inv; x1[x] *= inv; }
      }
      bf8 pk;
#pragma unroll
      for (int x = 0; x < 4; ++x) { pk[x] = f2b(x0[x]); pk[x + 4] = f2b(x1[x]); }
      *(bf8*)&As[row * 264 + k] = pk;
    }
  }
  __syncthreads();

  const int lane = t & 63, wv = t >> 6;
  const int lr = lane & 15;
  const int lq = lane >> 4;
  const int n0 = wv * 64;

  f4 acc[4][4];
#pragma unroll
  for (int a = 0; a < 4; ++a)
#pragma unroll
    for (int b = 0; b < 4; ++b) acc[a][b] = (f4)0.f;

  for (int kc = 0; kc < 256; kc += 32) {
    bf8 aF[4], bF[4];
#pragma unroll
    for (int a = 0; a < 4; ++a)
      aF[a] = *(const bf8*)&Wl1T[(size_t)(n0 + a * 16 + lr) * 256 + kc + lq * 8];
#pragma unroll
    for (int b = 0; b < 4; ++b)
      bF[b] = *(const bf8*)&As[(b * 16 + lr) * 264 + kc + lq * 8];
#pragma unroll
    for (int a = 0; a < 4; ++a)
#pragma unroll
      for (int b = 0; b < 4; ++b)
        acc[a][b] = __builtin_amdgcn_mfma_f32_16x16x32_bf16(aF[a], bF[b], acc[a][b], 0, 0, 0);
  }

#pragma unroll
  for (int b = 0; b < 4; ++b) {
    const int gn = v0 + b * 16 + lr;
    if (gn >= NN) continue;
#pragma unroll
    for (int a = 0; a < 4; ++a) {
      const int n = n0 + a * 16 + lq * 4;
      f4 bb = *(const f4*)&bl1[n];
      bf4v pk;
      pk[0] = f2b(fmaxf(acc[a][b][0] + bb[0], 0.f));
      pk[1] = f2b(fmaxf(acc[a][b][1] + bb[1], 0.f));
      pk[2] = f2b(fmaxf(acc[a][b][2] + bb[2], 0.f));
      pk[3] = f2b(fmaxf(acc[a][b][3] + bb[3], 0.f));
      *(bf4v*)&h1b[(size_t)gn * 256 + n] = pk;
    }
  }
}

// ---------------- final linear: out = concat(h1b, s2/cnt) @ Wl2 + bl2 ---------

__global__ __launch_bounds__(256) void out_k(
    const short* __restrict__ h1b, const float* __restrict__ s2,
    const int* __restrict__ cnt, const float* __restrict__ Wl2,
    const float* __restrict__ bl2, float* __restrict__ out)
{
  __shared__ float A8[8][512];
  const int n0 = blockIdx.x * 8;
  const int tx = threadIdx.x;
  const int ty = threadIdx.y;
  const int t = ty * 32 + tx;
  const int row = t >> 5;
  const int k0 = (t & 31) * 16;
  const int n = n0 + row;
  const float inv = 1.0f / fmaxf((float)cnt[n], 1.0f);
#pragma unroll
  for (int i = 0; i < 16; i += 4) {
    int k = k0 + i;
    f4 v;
    if (k < 256) {
      v = b2f4(*(const bf4v*)&h1b[(size_t)n * 256 + k]);
    } else {
      v = *(const f4*)&s2[(size_t)n * 256 + (k - 256)];
      v[0] *= inv; v[1] *= inv; v[2] *= inv; v[3] *= inv;
    }
    *(f4*)&A8[row][k] = v;
  }
  __syncthreads();
  float acc = bl2[tx];
#pragma unroll 8
  for (int k = 0; k < 512; k++) acc = fmaf(A8[ty][k], Wl2[(size_t)k * 32 + tx], acc);
  out[(size_t)(n0 + ty) * 32 + tx] = acc;
}

// ---------------- launch ------------------------------------------------------

extern "C" void kernel_launch(void* const* d_in, const int* in_sizes, int n_in,
                              void* d_out, int out_size, void* d_ws, size_t ws_size,
                              hipStream_t stream) {
  const float* nf   = (const float*)d_in[0];
  const float* ef   = (const float*)d_in[1];
  const int*   src  = (const int*)d_in[2];
  const int*   dst  = (const int*)d_in[3];
  const float* We1  = (const float*)d_in[4];
  const float* be1  = (const float*)d_in[5];
  const float* Wr1a = (const float*)d_in[6];
  const float* br1a = (const float*)d_in[7];
  const float* Wr1b = (const float*)d_in[8];
  const float* br1b = (const float*)d_in[9];
  const float* Wl1  = (const float*)d_in[10];
  const float* bl1  = (const float*)d_in[11];
  const float* We2  = (const float*)d_in[12];
  const float* be2  = (const float*)d_in[13];
  const float* Wr2a = (const float*)d_in[14];
  const float* br2a = (const float*)d_in[15];
  const float* Wr2b = (const float*)d_in[16];
  const float* br2b = (const float*)d_in[17];
  const float* Wl2  = (const float*)d_in[18];
  const float* bl2  = (const float*)d_in[19];

  float* ws = (float*)d_ws;
  float* s1   = ws;                             // N*128 f
  float* s2   = s1 + (size_t)NN * 128;          // N*256 f
  int*   cnt  = (int*)(s2 + (size_t)NN * 256);  // N
  short* h1b  = (short*)(cnt + NN);             // N*256 bf16
  short* nfb  = h1b + (size_t)NN * 256;         // N*128 bf16
  short* WaT1 = nfb + (size_t)NN * 128;         // 128*128 bf16
  short* WbT1 = WaT1 + 128 * 128;               // 128*128
  short* We2T = WbT1 + 128 * 128;               // 256*128
  short* WaT2 = We2T + 256 * 128;               // 256*256
  short* WbT2 = WaT2 + 256 * 256;               // 256*256
  short* Wl1T = WbT2 + 256 * 256;               // 256*256
  int*   off2 = (int*)(Wl1T + 256 * 256);       // N
  int*   perm = off2 + NN;                      // E
  int*   dsts = perm + NE;                      // E
  float* invn1 = (float*)(dsts + NE);           // N
  float* invn2 = invn1 + NN;                    // N
  int*   bsum  = (int*)(invn2 + NN);            // 64

  size_t need = ((size_t)NN * 128 + (size_t)NN * 256 + NN) * 4 +
                ((size_t)NN * 256 + (size_t)NN * 128 +
                 (size_t)128 * 128 * 2 + (size_t)256 * 128 +
                 (size_t)256 * 256 * 3) * 2 +
                ((size_t)NN + 2 * (size_t)NE + 2 * (size_t)NN) * 4 + 64 * 4;
  if (ws_size < need) return;

  // zero s1, s2, cnt (contiguous) first: prep_k accumulates cnt
  hipMemsetAsync(s1, 0, ((size_t)NN * 128 + (size_t)NN * 256 + NN) * 4, stream);

  // merged: 6 weight transposes + nf->bf16 + degree count
  prep_k<<<10399, 256, 0, stream>>>(Wr1a, Wr1b, We2, Wr2a, Wr2b, Wl1,
                                    WaT1, WbT1, We2T, WaT2, WbT2, Wl1T,
                                    nf, nfb, dst, cnt);
  norm1_k<<<(NN + 3) / 4, 256, 0, stream>>>(nfb, invn1);

  // hierarchical counting-sort scan (49 chunks of 1024)
  const int nb = (NN + 1023) / 1024;
  scanA_k<<<nb, 1024, 0, stream>>>(cnt, off2, bsum);
  scanB_k<<<1, 64, 0, stream>>>(bsum, nb);
  scanC_k<<<(NN + 255) / 256, 256, 0, stream>>>(off2, bsum);
  perm_k<<<NE / 256, 256, 0, stream>>>(dst, off2, perm, dsts);

  edge_mlp1<<<NWGE1, 512, 0, stream>>>(nfb, ef, src, perm, dsts, invn1,
                                       We1, be1, WaT1, br1a, WbT1, br1b, s1);

  h1m_k<<<(NN + 63) / 64, 256, 0, stream>>>(nf, s1, cnt, Wl1T, bl1, h1b);
  norm2_k<<<(NN + 3) / 4, 256, 0, stream>>>(h1b, invn2);

  edge_mlp2<<<NWGE2, 512, 0, stream>>>(h1b, ef, src, perm, dsts, invn2,
                                       We1, be1, We2T, be2, WaT2, br2a,
                                       WbT2, br2b, s2);

  out_k<<<NN / 8, dim3(32, 8), 0, stream>>>(h1b, s2, cnt, Wl2, bl2, (float*)d_out);
}